// Round 10
// baseline (11516.126 us; speedup 1.0000x reference)
//
#include <hip/hip_runtime.h>

// DKVMN forward, round 10 — table-driven, dim-chunked in-register recurrence.
// R9 diagnosis: kS VGPR_Count=60 -> m[16] (64 VGPRs) lived in SCRATCH, and the
// ~130 GB of L2 scratch traffic was the 5.8 ms wall (VALUBusy 16%). Fix: each
// thread owns 8 rows x 1 float4 (m[8]=32 regs, total demand ~60 = what the
// allocator grants). Block = (b, dim-chunk): ALL 512 rows x 64 dims -> r
// writes are EXCLUSIVE per block (no atomics, no partials, no memset).
//   kW: wtab[513][512] fp32   kG: etab/atab[1025][256] fp32  (3.2 MB, L2-hot)
//   kS: 1024 blocks x 1024 thr; w staged in LDS per 16-step tile; e/a read
//       directly from tables (L1 broadcast); r reduced via LDS atomics.
//   kM: MLP over all 131072 (b,t).
// ws = 3.2 MB + 128 MiB fp32 r ~ 131 MiB.

#define B_ 256
#define T_ 512
#define N_ 512
#define DK_ 64
#define DV_ 256
#define S_ 64
#define NP_ (B_ * T_)
#define NCID 513
#define NIID 1025
#define TB_ 16

typedef _Float16 h16;
typedef __attribute__((ext_vector_type(4))) _Float16 half4;

__device__ __forceinline__ float dot4(float4 a, float4 b) {
  return a.x * b.x + a.y * b.y + a.z * b.z + a.w * b.w;
}
__device__ __forceinline__ float4 h2f(half4 h) {
  return make_float4((float)h.x, (float)h.y, (float)h.z, (float)h.w);
}

// ============ kW: wtab[c][n] = softmax_n(q_c . K_n), 513 blocks ============
__global__ __launch_bounds__(512) void kW(const float* __restrict__ Kmem,
                                          const float* __restrict__ cemb,
                                          float* __restrict__ wtab) {
  __shared__ float s_q[DK_];
  __shared__ float s_red[16];
  const int tid = threadIdx.x, c = blockIdx.x;
  if (tid < DK_) s_q[tid] = c ? cemb[c * DK_ + tid] : 0.f;
  __syncthreads();
  const int n = tid;  // 512 threads = N
  const float4* kr = (const float4*)(Kmem + n * DK_);
  float acc = 0.f;
#pragma unroll
  for (int kk = 0; kk < DK_ / 4; ++kk) acc += dot4(kr[kk], *(const float4*)&s_q[kk * 4]);
  const int lane = tid & 63, wid = tid >> 6;
  float mx = acc;
  for (int off = 32; off; off >>= 1) mx = fmaxf(mx, __shfl_xor(mx, off, 64));
  if (lane == 0) s_red[wid] = mx;
  __syncthreads();
  float gmx = s_red[0];
#pragma unroll
  for (int i = 1; i < 8; ++i) gmx = fmaxf(gmx, s_red[i]);
  const float e = expf(acc - gmx);
  float sum = e;
  for (int off = 32; off; off >>= 1) sum += __shfl_xor(sum, off, 64);
  if (lane == 0) s_red[8 + wid] = sum;
  __syncthreads();
  float gs = 0.f;
#pragma unroll
  for (int i = 0; i < 8; ++i) gs += s_red[8 + i];
  wtab[c * N_ + n] = e / gs;
}

// ============ kG: etab/atab[id][d], 129 blocks x 8 ids =====================
__global__ __launch_bounds__(512) void kG(const float* __restrict__ iemb,
                                          const float* __restrict__ We,
                                          const float* __restrict__ be,
                                          const float* __restrict__ Wa,
                                          const float* __restrict__ ba,
                                          float* __restrict__ etab,
                                          float* __restrict__ atab) {
  __shared__ float s_v[8 * DV_];  // 8 KB
  const int tid = threadIdx.x, bi = blockIdx.x;
  {
    const int j = tid >> 6, c4 = tid & 63;
    const int id = bi * 8 + j;
    float4 v = make_float4(0.f, 0.f, 0.f, 0.f);
    if (id >= 1 && id < NIID) v = ((const float4*)iemb)[(size_t)id * 64 + c4];
    *(float4*)&s_v[j * DV_ + c4 * 4] = v;
  }
  __syncthreads();
  const int gate = tid >> 8, d = tid & 255;  // gate wave-uniform
  const float4* wr = (const float4*)((gate ? Wa : We) + d * DV_);
  float acc[8];
#pragma unroll
  for (int j = 0; j < 8; ++j) acc[j] = 0.f;
  for (int kk = 0; kk < DV_ / 4; ++kk) {
    const float4 w4 = wr[kk];
#pragma unroll
    for (int j = 0; j < 8; ++j) acc[j] += dot4(w4, *(const float4*)&s_v[j * DV_ + kk * 4]);
  }
  const float bias = gate ? ba[d] : be[d];
#pragma unroll
  for (int j = 0; j < 8; ++j) {
    const int id = bi * 8 + j;
    if (id < NIID) {
      if (gate) atab[(size_t)id * DV_ + d] = tanhf(acc[j] + bias);
      else      etab[(size_t)id * DV_ + d] = 1.f / (1.f + expf(-(acc[j] + bias)));
    }
  }
}

// ============ kS: dim-chunked in-register recurrence =======================
// 1024 blocks = (b, dc); block owns all 512 rows x 64 dims. 1024 threads:
// thread = (rg = tid>>4: rows rg*8..+7, col = tid&15: float4 within chunk).
// m[8] = 32 VGPRs of true state. r written exclusively (no global atomics).
__global__ __launch_bounds__(1024) void kS(
    const int* __restrict__ concepts, const int* __restrict__ inter,
    const float* __restrict__ Vmem, const float* __restrict__ wtab,
    const float* __restrict__ etab, const float* __restrict__ atab,
    float* __restrict__ r) {
  __shared__ float s_wt[TB_][N_];     // 32 KB  w for all 512 rows x 16 steps
  __shared__ float s_rt[TB_][16][4];  // 4 KB   r partials per (step, col)
  const int tid = threadIdx.x, bx = blockIdx.x;
  const int b = bx >> 2, dc = bx & 3;
  const int rg = tid >> 4, col = tid & 15;
  const int d4 = dc * 16 + col;  // this thread's float4-dim in [0,64)
  float4 m[8];
  {
    const float4* vm4 = (const float4*)Vmem;
#pragma unroll
    for (int i = 0; i < 8; ++i) m[i] = vm4[(size_t)(rg * 8 + i) * 64 + d4];
  }
  const int* cb = concepts + b * T_;
  const int* ib = inter + b * T_;
  const float4* wtab4 = (const float4*)wtab;
  const float4* etab4 = (const float4*)etab;
  const float4* atab4 = (const float4*)atab;
  float4* r4 = (float4*)r + (size_t)b * T_ * 64;

  for (int t0 = 0; t0 < T_; t0 += TB_) {
    // ---- stage w tile (16 x 512 fp32); zero r partials ----
#pragma unroll
    for (int i = 0; i < 2; ++i) {
      const int f = tid + i * 1024;  // 0..2047 float4
      const int tl = f >> 7, q = f & 127;
      const int c = cb[t0 + tl];
      ((float4*)s_wt)[f] = wtab4[(size_t)c * 128 + q];
    }
    if (tid < 256) ((float4*)s_rt)[tid] = make_float4(0.f, 0.f, 0.f, 0.f);
    __syncthreads();

    // ---- 16 timesteps over register-resident state ----
    for (int tl = 0; tl < TB_; ++tl) {
      const int iv = ib[t0 + tl];  // block-uniform -> scalar load
      const float4 e4 = etab4[(size_t)iv * 64 + d4];  // L1-broadcast across waves
      const float4 a4 = atab4[(size_t)iv * 64 + d4];
      const float4 wA = *(const float4*)&s_wt[tl][rg * 8];
      const float4 wB = *(const float4*)&s_wt[tl][rg * 8 + 4];
      float4 racc = make_float4(0.f, 0.f, 0.f, 0.f);
#pragma unroll
      for (int i = 0; i < 8; ++i) {
        const float w = (i == 0) ? wA.x : (i == 1) ? wA.y : (i == 2) ? wA.z
                      : (i == 3) ? wA.w : (i == 4) ? wB.x : (i == 5) ? wB.y
                      : (i == 6) ? wB.z : wB.w;
        racc.x = fmaf(w, m[i].x, racc.x);
        racc.y = fmaf(w, m[i].y, racc.y);
        racc.z = fmaf(w, m[i].z, racc.z);
        racc.w = fmaf(w, m[i].w, racc.w);
        m[i].x = fmaf(-w, fmaf(e4.x, m[i].x, -a4.x), m[i].x);
        m[i].y = fmaf(-w, fmaf(e4.y, m[i].y, -a4.y), m[i].y);
        m[i].z = fmaf(-w, fmaf(e4.z, m[i].z, -a4.z), m[i].z);
        m[i].w = fmaf(-w, fmaf(e4.w, m[i].w, -a4.w), m[i].w);
      }
      atomicAdd(&s_rt[tl][col][0], racc.x);
      atomicAdd(&s_rt[tl][col][1], racc.y);
      atomicAdd(&s_rt[tl][col][2], racc.z);
      atomicAdd(&s_rt[tl][col][3], racc.w);
    }
    __syncthreads();

    // ---- exclusive drain: r[t][dc-slice], fp32, no atomics ----
    if (tid < 256) {
      const int tl = tid >> 4, cc = tid & 15;
      const float4 v = *(const float4*)&s_rt[tl][cc][0];
      r4[(size_t)(t0 + tl) * 64 + dc * 16 + cc] = v;
    }
    __syncthreads();  // s_rt/s_wt reads done before next tile restages
  }
}

// ============ kM: MLP head, 2048 blocks x 512 thr ==========================
#define MP_ 64
__global__ __launch_bounds__(512) void kM(const int* __restrict__ concepts,
                                          const float* __restrict__ cemb,
                                          const float* __restrict__ r,
                                          const float* __restrict__ W1,
                                          const float* __restrict__ b1,
                                          const float* __restrict__ W2,
                                          const float* __restrict__ b2,
                                          const float* __restrict__ W3,
                                          const float* __restrict__ b3,
                                          float* __restrict__ out) {
  __shared__ float s_f[MP_][DV_ + DK_];  // 80 KB
  __shared__ h16 s_W1[S_][324];          // 40.5 KB (padded)
  __shared__ float s_h1[8][8][S_];       // 16 KB
  __shared__ int s_c[MP_];
  const int tid = threadIdx.x, g = blockIdx.x;
  const int lane = tid & 63, wv = tid >> 6;
  if (tid < MP_) s_c[tid] = concepts[g * MP_ + tid];
  for (int idx = tid; idx < S_ * 320; idx += 512) {
    const int j = idx / 320, k = idx % 320;
    s_W1[j][k] = (h16)W1[j * 320 + k];
  }
  __syncthreads();
  {
    const float4* r4 = (const float4*)r;
#pragma unroll
    for (int i = 0; i < 8; ++i) {
      const int idx = tid + i * 512, p = idx >> 6, c4 = idx & 63;
      *(float4*)&s_f[p][c4 * 4] = r4[(size_t)(g * MP_ + p) * 64 + c4];
    }
    const float4* ce4 = (const float4*)cemb;
    const float4 z = make_float4(0.f, 0.f, 0.f, 0.f);
#pragma unroll
    for (int i = 0; i < 2; ++i) {
      const int idx = tid + i * 512, p = idx >> 4, k4 = idx & 15;
      const int c = s_c[p];
      *(float4*)&s_f[p][DV_ + k4 * 4] = c ? ce4[c * 16 + k4] : z;
    }
  }
  __syncthreads();
  const int j = lane;  // neuron
  float acc[8];
  {
    const float b1j = b1[j];
#pragma unroll
    for (int p = 0; p < 8; ++p) acc[p] = b1j;
  }
  for (int k4 = 0; k4 < 80; ++k4) {
    const float4 w4 = h2f(*(const half4*)&s_W1[j][k4 * 4]);
#pragma unroll
    for (int p = 0; p < 8; ++p)
      acc[p] += dot4(w4, *(const float4*)&s_f[wv * 8 + p][k4 * 4]);
  }
#pragma unroll
  for (int p = 0; p < 8; ++p) s_h1[wv][p][j] = fmaxf(acc[p], 0.f);
  __syncthreads();
  {
    const float b2j = b2[j];
#pragma unroll
    for (int p = 0; p < 8; ++p) acc[p] = b2j;
  }
  const float4* w2r = (const float4*)(W2 + j * S_);
#pragma unroll
  for (int k4 = 0; k4 < S_ / 4; ++k4) {
    const float4 w4 = w2r[k4];
#pragma unroll
    for (int p = 0; p < 8; ++p)
      acc[p] += dot4(w4, *(const float4*)&s_h1[wv][p][k4 * 4]);
  }
  const float w3j = W3[j], b3v = b3[0];
#pragma unroll
  for (int p = 0; p < 8; ++p) {
    float pp = fmaxf(acc[p], 0.f) * w3j;
    for (int off = 32; off; off >>= 1) pp += __shfl_xor(pp, off, 64);
    if (lane == 0)
      out[g * MP_ + wv * 8 + p] = 1.f / (1.f + expf(-(pp + b3v)));
  }
}

extern "C" void kernel_launch(void* const* d_in, const int* in_sizes, int n_in,
                              void* d_out, int out_size, void* d_ws, size_t ws_size,
                              hipStream_t stream) {
  const int* concepts = (const int*)d_in[0];
  const int* interactions = (const int*)d_in[1];
  const float* Kmem = (const float*)d_in[2];
  const float* Vmem = (const float*)d_in[3];
  const float* cemb = (const float*)d_in[4];
  const float* iemb = (const float*)d_in[5];
  const float* We = (const float*)d_in[6];
  const float* be = (const float*)d_in[7];
  const float* Wa = (const float*)d_in[8];
  const float* ba = (const float*)d_in[9];
  const float* W1 = (const float*)d_in[10];
  const float* b1 = (const float*)d_in[11];
  const float* W2 = (const float*)d_in[12];
  const float* b2 = (const float*)d_in[13];
  const float* W3 = (const float*)d_in[14];
  const float* b3 = (const float*)d_in[15];
  float* out = (float*)d_out;

  const size_t sz_w = (size_t)NCID * N_ * 4;    // 1.05 MB
  const size_t sz_e = (size_t)NIID * DV_ * 4;   // 1.05 MB
  float* wtab = (float*)d_ws;
  float* etab = (float*)((char*)d_ws + sz_w);
  float* atab = (float*)((char*)d_ws + sz_w + sz_e);
  float* r    = (float*)((char*)d_ws + sz_w + 2 * sz_e);  // 128 MiB fp32

  kW<<<dim3(NCID), dim3(512), 0, stream>>>(Kmem, cemb, wtab);
  kG<<<dim3((NIID + 7) / 8), dim3(512), 0, stream>>>(iemb, We, be, Wa, ba, etab, atab);
  kS<<<dim3(B_ * 4), dim3(1024), 0, stream>>>(concepts, interactions, Vmem,
                                              wtab, etab, atab, r);
  kM<<<dim3(NP_ / MP_), dim3(512), 0, stream>>>(concepts, cemb, r,
                                                W1, b1, W2, b2, W3, b3, out);
}

// Round 11
// 6456.239 us; speedup vs baseline: 1.7837x; 1.7837x over previous
//
#include <hip/hip_runtime.h>

// DKVMN forward, round 11 — table-driven; LDS-pipe-lean in-register recurrence.
// R9/R10 re-diagnosis: kS was LDS-PIPE-bound (one pipe/CU): 96 LDS-cyc per
// wave-step (4 b128 w + 2 b128 e/a + 4 atomics) x 16 waves >> 384 VALU-cyc
// per SIMD -> VALUBusy ~16%. Fixes:
//  * w reads are wave-uniform -> scalar loads from L2-hot wtab via
//    readfirstlane-forced uniform pointer (zero LDS, no staging).
//  * NTB=512 + waves_per_eu(2): the only proven 128-VGPR grant (R5/R6), so
//    m[16] (64 regs) truly lives in registers. LDS 48KB -> 2 blocks/CU.
//  * r merge: fp16 partial regions (no atomics; needs 259 MiB ws) else
//    global fp32 atomicAdd with chunk-decorrelated drain order (137 MiB).
// kW: wtab[513][512]  kG: etab/atab[1025][256]  kM: MLP for all (b,t).

#define B_ 256
#define T_ 512
#define N_ 512
#define DK_ 64
#define DV_ 256
#define S_ 64
#define NP_ (B_ * T_)
#define NCID 513
#define NIID 1025
#define TB_ 16

typedef _Float16 h16;
typedef __attribute__((ext_vector_type(4))) _Float16 half4;

__device__ __forceinline__ float dot4(float4 a, float4 b) {
  return a.x * b.x + a.y * b.y + a.z * b.z + a.w * b.w;
}
__device__ __forceinline__ float4 h2f(half4 h) {
  return make_float4((float)h.x, (float)h.y, (float)h.z, (float)h.w);
}
__device__ __forceinline__ half4 f2h(float4 f) {
  half4 h;
  h.x = (h16)f.x; h.y = (h16)f.y; h.z = (h16)f.z; h.w = (h16)f.w;
  return h;
}

// ============ kW: wtab[c][n] = softmax_n(q_c . K_n), 513 blocks ============
__global__ __launch_bounds__(512) void kW(const float* __restrict__ Kmem,
                                          const float* __restrict__ cemb,
                                          float* __restrict__ wtab) {
  __shared__ float s_q[DK_];
  __shared__ float s_red[16];
  const int tid = threadIdx.x, c = blockIdx.x;
  if (tid < DK_) s_q[tid] = c ? cemb[c * DK_ + tid] : 0.f;
  __syncthreads();
  const int n = tid;
  const float4* kr = (const float4*)(Kmem + n * DK_);
  float acc = 0.f;
#pragma unroll
  for (int kk = 0; kk < DK_ / 4; ++kk) acc += dot4(kr[kk], *(const float4*)&s_q[kk * 4]);
  const int lane = tid & 63, wid = tid >> 6;
  float mx = acc;
  for (int off = 32; off; off >>= 1) mx = fmaxf(mx, __shfl_xor(mx, off, 64));
  if (lane == 0) s_red[wid] = mx;
  __syncthreads();
  float gmx = s_red[0];
#pragma unroll
  for (int i = 1; i < 8; ++i) gmx = fmaxf(gmx, s_red[i]);
  const float e = expf(acc - gmx);
  float sum = e;
  for (int off = 32; off; off >>= 1) sum += __shfl_xor(sum, off, 64);
  if (lane == 0) s_red[8 + wid] = sum;
  __syncthreads();
  float gs = 0.f;
#pragma unroll
  for (int i = 0; i < 8; ++i) gs += s_red[8 + i];
  wtab[c * N_ + n] = e / gs;
}

// ============ kG: etab/atab[id][d], 129 blocks x 8 ids =====================
__global__ __launch_bounds__(512) void kG(const float* __restrict__ iemb,
                                          const float* __restrict__ We,
                                          const float* __restrict__ be,
                                          const float* __restrict__ Wa,
                                          const float* __restrict__ ba,
                                          float* __restrict__ etab,
                                          float* __restrict__ atab) {
  __shared__ float s_v[8 * DV_];
  const int tid = threadIdx.x, bi = blockIdx.x;
  {
    const int j = tid >> 6, c4 = tid & 63;
    const int id = bi * 8 + j;
    float4 v = make_float4(0.f, 0.f, 0.f, 0.f);
    if (id >= 1 && id < NIID) v = ((const float4*)iemb)[(size_t)id * 64 + c4];
    *(float4*)&s_v[j * DV_ + c4 * 4] = v;
  }
  __syncthreads();
  const int gate = tid >> 8, d = tid & 255;
  const float4* wr = (const float4*)((gate ? Wa : We) + d * DV_);
  float acc[8];
#pragma unroll
  for (int j = 0; j < 8; ++j) acc[j] = 0.f;
  for (int kk = 0; kk < DV_ / 4; ++kk) {
    const float4 w4 = wr[kk];
#pragma unroll
    for (int j = 0; j < 8; ++j) acc[j] += dot4(w4, *(const float4*)&s_v[j * DV_ + kk * 4]);
  }
  const float bias = gate ? ba[d] : be[d];
#pragma unroll
  for (int j = 0; j < 8; ++j) {
    const int id = bi * 8 + j;
    if (id < NIID) {
      if (gate) atab[(size_t)id * DV_ + d] = tanhf(acc[j] + bias);
      else      etab[(size_t)id * DV_ + d] = 1.f / (1.f + expf(-(acc[j] + bias)));
    }
  }
}

// ============ kS: in-register recurrence, 1024 blocks x 512 thr ============
// block = (b, ch∈0..3); 8 waves x 16 rows; lane owns d4. m[16] = 64 VGPRs.
template <bool PART>
__global__ void __attribute__((amdgpu_flat_work_group_size(512, 512),
                               amdgpu_waves_per_eu(2)))
kS(const int* __restrict__ concepts, const int* __restrict__ inter,
   const float* __restrict__ Vmem, const float* __restrict__ wtab,
   const float* __restrict__ etab, const float* __restrict__ atab,
   float* __restrict__ r, h16* __restrict__ rp) {
  __shared__ float s_e[TB_][DV_];     // 16 KB
  __shared__ float s_a[TB_][DV_];     // 16 KB
  __shared__ float s_rt[TB_][4][64];  // 16 KB, lane-indexed planes (no conflicts)
  const int tid = threadIdx.x, bx = blockIdx.x;
  const int b = bx >> 2, ch = bx & 3;
  const int lane = tid & 63, wv = tid >> 6;
  // wave-uniform row base (forced into SGPR so w-loads scalarize)
  const int row0u = ch * 128 + __builtin_amdgcn_readfirstlane(wv * 16);
  float4 m[16];
  {
    const float4* vm4 = (const float4*)Vmem;
#pragma unroll
    for (int i = 0; i < 16; ++i) m[i] = vm4[(size_t)(row0u + i) * 64 + lane];
  }
  const int* cb = concepts + b * T_;
  const int* ib = inter + b * T_;
  const float4* etab4 = (const float4*)etab;
  const float4* atab4 = (const float4*)atab;
  float* rb = r + (size_t)b * T_ * DV_;
  h16* rpb = rp + (size_t)ch * NP_ * DV_ + (size_t)b * T_ * DV_;

  for (int t0 = 0; t0 < T_; t0 += TB_) {
    // ---- stage e/a tiles; zero r planes ----
#pragma unroll
    for (int i = 0; i < 4; ++i) {
      const int idx = tid + i * 512;  // 0..2047 float4 (16 tl x (64 e + 64 a))
      const int tl = idx >> 7, half = (idx >> 6) & 1, c4 = idx & 63;
      const int iv = ib[t0 + tl];
      if (half == 0)
        *(float4*)&s_e[tl][c4 * 4] = etab4[(size_t)iv * 64 + c4];
      else
        *(float4*)&s_a[tl][c4 * 4] = atab4[(size_t)iv * 64 + c4];
    }
    ((float4*)s_rt)[tid] = make_float4(0.f, 0.f, 0.f, 0.f);
    ((float4*)s_rt)[tid + 512] = make_float4(0.f, 0.f, 0.f, 0.f);
    __syncthreads();

    // ---- 16 timesteps over register-resident state ----
    for (int tl = 0; tl < TB_; ++tl) {
      // wave-uniform w: scalar loads from L2-hot table (no LDS)
      const float* wp = wtab + (size_t)cb[t0 + tl] * N_ + row0u;
      const float4 w0 = *(const float4*)(wp + 0);
      const float4 w1 = *(const float4*)(wp + 4);
      const float4 w2 = *(const float4*)(wp + 8);
      const float4 w3 = *(const float4*)(wp + 12);
      const float4 e4 = *(const float4*)&s_e[tl][lane * 4];
      const float4 a4 = *(const float4*)&s_a[tl][lane * 4];
      float4 racc = make_float4(0.f, 0.f, 0.f, 0.f);
#pragma unroll
      for (int i = 0; i < 16; ++i) {
        const float w = (i < 4) ? ((i == 0) ? w0.x : (i == 1) ? w0.y : (i == 2) ? w0.z : w0.w)
                      : (i < 8) ? ((i == 4) ? w1.x : (i == 5) ? w1.y : (i == 6) ? w1.z : w1.w)
                      : (i < 12) ? ((i == 8) ? w2.x : (i == 9) ? w2.y : (i == 10) ? w2.z : w2.w)
                                 : ((i == 12) ? w3.x : (i == 13) ? w3.y : (i == 14) ? w3.z : w3.w);
        racc.x = fmaf(w, m[i].x, racc.x);
        racc.y = fmaf(w, m[i].y, racc.y);
        racc.z = fmaf(w, m[i].z, racc.z);
        racc.w = fmaf(w, m[i].w, racc.w);
        m[i].x = fmaf(-w, fmaf(e4.x, m[i].x, -a4.x), m[i].x);
        m[i].y = fmaf(-w, fmaf(e4.y, m[i].y, -a4.y), m[i].y);
        m[i].z = fmaf(-w, fmaf(e4.z, m[i].z, -a4.z), m[i].z);
        m[i].w = fmaf(-w, fmaf(e4.w, m[i].w, -a4.w), m[i].w);
      }
      // lane-indexed LDS atomics: 64 distinct addresses, conflict-free
      atomicAdd(&s_rt[tl][0][lane], racc.x);
      atomicAdd(&s_rt[tl][1][lane], racc.y);
      atomicAdd(&s_rt[tl][2][lane], racc.z);
      atomicAdd(&s_rt[tl][3][lane], racc.w);
    }
    __syncthreads();

    // ---- drain ----
    if (PART) {
      // exclusive fp16 partial region, no atomics
#pragma unroll
      for (int i = 0; i < 2; ++i) {
        const int idx = tid + i * 512;  // 0..1023 half4
        const int tl = idx >> 6, d4 = idx & 63;
        const float4 v = make_float4(s_rt[tl][0][d4], s_rt[tl][1][d4],
                                     s_rt[tl][2][d4], s_rt[tl][3][d4]);
        *(half4*)(rpb + (size_t)(t0 + tl) * DV_ + d4 * 4) = f2h(v);
      }
    } else {
      // global fp32 atomics, drain order decorrelated across chunks
#pragma unroll
      for (int i = 0; i < 8; ++i) {
        const int j = (i + ch * 2) & 7;
        const int idx = tid + j * 512;  // 0..4095 floats
        const int tl = idx >> 8, d = idx & 255;
        atomicAdd(&rb[(size_t)(t0 + tl) * DV_ + d], s_rt[tl][d & 3][d >> 2]);
      }
    }
    __syncthreads();
  }
}

// ============ kM: MLP head, 2048 blocks x 512 thr ==========================
#define MP_ 64
template <bool PART>
__global__ __launch_bounds__(512) void kM(const int* __restrict__ concepts,
                                          const float* __restrict__ cemb,
                                          const float* __restrict__ r,
                                          const h16* __restrict__ rp,
                                          const float* __restrict__ W1,
                                          const float* __restrict__ b1,
                                          const float* __restrict__ W2,
                                          const float* __restrict__ b2,
                                          const float* __restrict__ W3,
                                          const float* __restrict__ b3,
                                          float* __restrict__ out) {
  __shared__ float s_f[MP_][DV_ + DK_];  // 80 KB
  __shared__ h16 s_W1[S_][324];          // 40.5 KB (padded)
  __shared__ float s_h1[8][8][S_];       // 16 KB
  __shared__ int s_c[MP_];
  const int tid = threadIdx.x, g = blockIdx.x;
  const int lane = tid & 63, wv = tid >> 6;
  if (tid < MP_) s_c[tid] = concepts[g * MP_ + tid];
  for (int idx = tid; idx < S_ * 320; idx += 512) {
    const int j = idx / 320, k = idx % 320;
    s_W1[j][k] = (h16)W1[j * 320 + k];
  }
  __syncthreads();
  {
    const size_t SZR4 = (size_t)NP_ * 64;  // region stride in half4
    const half4* q = (const half4*)rp;
    const float4* r4 = (const float4*)r;
#pragma unroll
    for (int i = 0; i < 8; ++i) {
      const int idx = tid + i * 512, p = idx >> 6, c4 = idx & 63;
      const size_t off = (size_t)(g * MP_ + p) * 64 + c4;
      float4 v;
      if (PART) {
        const float4 v0 = h2f(q[off]);
        const float4 v1 = h2f(q[off + SZR4]);
        const float4 v2 = h2f(q[off + 2 * SZR4]);
        const float4 v3 = h2f(q[off + 3 * SZR4]);
        v = make_float4(v0.x + v1.x + v2.x + v3.x, v0.y + v1.y + v2.y + v3.y,
                        v0.z + v1.z + v2.z + v3.z, v0.w + v1.w + v2.w + v3.w);
      } else {
        v = r4[off];
      }
      *(float4*)&s_f[p][c4 * 4] = v;
    }
    const float4* ce4 = (const float4*)cemb;
    const float4 z = make_float4(0.f, 0.f, 0.f, 0.f);
#pragma unroll
    for (int i = 0; i < 2; ++i) {
      const int idx = tid + i * 512, p = idx >> 4, k4 = idx & 15;
      const int c = s_c[p];
      *(float4*)&s_f[p][DV_ + k4 * 4] = c ? ce4[c * 16 + k4] : z;
    }
  }
  __syncthreads();
  const int j = lane;
  float acc[8];
  {
    const float b1j = b1[j];
#pragma unroll
    for (int p = 0; p < 8; ++p) acc[p] = b1j;
  }
  for (int k4 = 0; k4 < 80; ++k4) {
    const float4 w4 = h2f(*(const half4*)&s_W1[j][k4 * 4]);
#pragma unroll
    for (int p = 0; p < 8; ++p)
      acc[p] += dot4(w4, *(const float4*)&s_f[wv * 8 + p][k4 * 4]);
  }
#pragma unroll
  for (int p = 0; p < 8; ++p) s_h1[wv][p][j] = fmaxf(acc[p], 0.f);
  __syncthreads();
  {
    const float b2j = b2[j];
#pragma unroll
    for (int p = 0; p < 8; ++p) acc[p] = b2j;
  }
  const float4* w2r = (const float4*)(W2 + j * S_);
#pragma unroll
  for (int k4 = 0; k4 < S_ / 4; ++k4) {
    const float4 w4 = w2r[k4];
#pragma unroll
    for (int p = 0; p < 8; ++p)
      acc[p] += dot4(w4, *(const float4*)&s_h1[wv][p][k4 * 4]);
  }
  const float w3j = W3[j], b3v = b3[0];
#pragma unroll
  for (int p = 0; p < 8; ++p) {
    float pp = fmaxf(acc[p], 0.f) * w3j;
    for (int off = 32; off; off >>= 1) pp += __shfl_xor(pp, off, 64);
    if (lane == 0)
      out[g * MP_ + wv * 8 + p] = 1.f / (1.f + expf(-(pp + b3v)));
  }
}

extern "C" void kernel_launch(void* const* d_in, const int* in_sizes, int n_in,
                              void* d_out, int out_size, void* d_ws, size_t ws_size,
                              hipStream_t stream) {
  const int* concepts = (const int*)d_in[0];
  const int* interactions = (const int*)d_in[1];
  const float* Kmem = (const float*)d_in[2];
  const float* Vmem = (const float*)d_in[3];
  const float* cemb = (const float*)d_in[4];
  const float* iemb = (const float*)d_in[5];
  const float* We = (const float*)d_in[6];
  const float* be = (const float*)d_in[7];
  const float* Wa = (const float*)d_in[8];
  const float* ba = (const float*)d_in[9];
  const float* W1 = (const float*)d_in[10];
  const float* b1 = (const float*)d_in[11];
  const float* W2 = (const float*)d_in[12];
  const float* b2 = (const float*)d_in[13];
  const float* W3 = (const float*)d_in[14];
  const float* b3 = (const float*)d_in[15];
  float* out = (float*)d_out;

  const size_t sz_w = (size_t)NCID * N_ * 4;
  const size_t sz_e = (size_t)NIID * DV_ * 4;
  const size_t tabs = sz_w + 2 * sz_e;                    // 3.15 MB
  const size_t sz_part = 4 * (size_t)NP_ * DV_ * 2;       // 256 MiB
  const size_t sz_r = (size_t)NP_ * DV_ * 4;              // 128 MiB
  float* wtab = (float*)d_ws;
  float* etab = (float*)((char*)d_ws + sz_w);
  float* atab = (float*)((char*)d_ws + sz_w + sz_e);
  char* tail = (char*)d_ws + tabs;

  kW<<<dim3(NCID), dim3(512), 0, stream>>>(Kmem, cemb, wtab);
  kG<<<dim3((NIID + 7) / 8), dim3(512), 0, stream>>>(iemb, We, be, Wa, ba, etab, atab);

  if (ws_size >= tabs + sz_part) {
    h16* rp = (h16*)tail;
    kS<true><<<dim3(B_ * 4), dim3(512), 0, stream>>>(
        concepts, interactions, Vmem, wtab, etab, atab, (float*)nullptr, rp);
    kM<true><<<dim3(NP_ / MP_), dim3(512), 0, stream>>>(
        concepts, cemb, (const float*)nullptr, rp, W1, b1, W2, b2, W3, b3, out);
  } else {
    float* r = (float*)tail;
    hipMemsetAsync(r, 0, sz_r, stream);
    kS<false><<<dim3(B_ * 4), dim3(512), 0, stream>>>(
        concepts, interactions, Vmem, wtab, etab, atab, r, (h16*)nullptr);
    kM<false><<<dim3(NP_ / MP_), dim3(512), 0, stream>>>(
        concepts, cemb, r, (const h16*)nullptr, W1, b1, W2, b2, W3, b3, out);
  }
}